// Round 1
// baseline (1116.887 us; speedup 1.0000x reference)
//
#include <hip/hip_runtime.h>
#include <math.h>

#define NTHREADS 256

// ---- LDS layout (floats). Rows are zero-padded: left pad 4, right pad
// covers max tap overhang, so conv loops need NO bounds checks and all
// reads are 16B-aligned ds_read_b128 with lane-stride-1 (conflict-free).
#define SX        0      // 6 rows  x stride 208, data at [4,204)   (xn, 200)
#define SX_STRIDE 208
#define SH1       1248   // 32 rows x stride 220, data at [4,208)   (h1: 204; reused for h3: 196)
#define SH1_STRIDE 220
#define SH2       8288   // 32 rows x stride 212, data at [4,204)   (h2: 200)
#define SH2_STRIDE 212
#define SF        15072  // 192
#define SZ1       15264  // 50 (padded 64)
#define SZ2       15328  // 50 (padded 64)
#define SZV       15392  // 15 (padded 16)
#define SMEM_TOTAL 15408 // 61,632 B  (< 64 KiB static limit; 2 blocks/CU)

__device__ __forceinline__ float gelu_f(float v) {
    return 0.5f * v * (1.0f + erff(v * 0.70710678118654752f));
}

// One Jacobi rotation in plane (p,q). All operands are named scalars (stay in
// VGPRs, no scratch). Sxp/Sxq are the two off-plane cross terms.
#define JROT(Spp, Sqq, Spq, Sxp, Sxq, Vp0, Vq0, Vp1, Vq1, Vp2, Vq2)          \
    if (fabsf(Spq) > 1e-18f) {                                               \
        float tau = (Sqq - Spp) / (2.0f * Spq);                              \
        float tj = copysignf(1.0f, tau) / (fabsf(tau) + sqrtf(1.0f + tau*tau)); \
        float cj = 1.0f / sqrtf(1.0f + tj*tj);                               \
        float sj = tj * cj;                                                  \
        Spp -= tj * Spq; Sqq += tj * Spq; Spq = 0.0f;                        \
        float tmp0 = Sxp; Sxp = cj*tmp0 - sj*Sxq; Sxq = sj*tmp0 + cj*Sxq;    \
        float tv;                                                            \
        tv = Vp0; Vp0 = cj*tv - sj*Vq0; Vq0 = sj*tv + cj*Vq0;                \
        tv = Vp1; Vp1 = cj*tv - sj*Vq1; Vq1 = sj*tv + cj*Vq1;                \
        tv = Vp2; Vp2 = cj*tv - sj*Vq2; Vq2 = sj*tv + cj*Vq2;                \
    }

__global__ void __launch_bounds__(NTHREADS)
rminet_kernel(const float* __restrict__ x,
              const float* __restrict__ calib,
              const float* __restrict__ biasv,
              const float* __restrict__ cw1, const float* __restrict__ cb1,
              const float* __restrict__ cw2, const float* __restrict__ cb2,
              const float* __restrict__ cw3, const float* __restrict__ cb3,
              const float* __restrict__ cw4, const float* __restrict__ cb4,
              const float* __restrict__ lw1, const float* __restrict__ lb1,
              const float* __restrict__ lw2, const float* __restrict__ lb2,
              const float* __restrict__ lw3, const float* __restrict__ lb3,
              float* __restrict__ out)
{
    __shared__ __align__(16) float sm[SMEM_TOTAL];
    const int tid  = threadIdx.x;
    const int b    = blockIdx.x;
    const int lane = tid & 63;
    // wave id, forced wave-uniform so per-wave channel-group weight addresses
    // become SGPR (s_load) instead of per-lane VMEM.
    const int cgw  = __builtin_amdgcn_readfirstlane(tid >> 6); // 0..3

    // ---- zero all LDS (establishes the zero pads) ----
    for (int i4 = tid; i4 < SMEM_TOTAL / 4; i4 += NTHREADS)
        *(float4*)&sm[i4 * 4] = make_float4(0.f, 0.f, 0.f, 0.f);
    __syncthreads();

    // ---- load imu = x[b,1:7,:]  (1200 contiguous floats) ----
    const float* xb = x + (size_t)b * 1400 + 200;
    for (int idx = tid; idx < 1200; idx += NTHREADS) {
        int row = idx / 200;
        int col = idx - row * 200;
        sm[SX + row * SX_STRIDE + 4 + col] = xb[idx];
    }
    __syncthreads();

    // ---- calibration (M = I + calib) + bias + normalize, in place ----
    if (tid < 200) {
        float v[6];
        #pragma unroll
        for (int j = 0; j < 6; j++) v[j] = sm[SX + j * SX_STRIDE + 4 + tid];
        const float MEANS[6]  = {0.042766f, 0.0081577f, -0.015818f, 9.2993f, -0.087913f, -3.3231f};
        const float INVSTD[6] = {1.f/0.4142f, 1.f/0.3522f, 1.f/0.2881f, 1.f/1.474f, 1.f/0.6553f, 1.f/0.8728f};
        #pragma unroll
        for (int i = 0; i < 6; i++) {
            float acc = biasv[i];
            #pragma unroll
            for (int j = 0; j < 6; j++) {
                float m = calib[i * 6 + j] + ((i == j) ? 1.0f : 0.0f);
                acc = fmaf(m, v[j], acc);
            }
            sm[SX + i * SX_STRIDE + 4 + tid] = (acc - MEANS[i]) * INVSTD[i];
        }
    }
    __syncthreads();

    // ---- conv1: 6ch(len200) -> 32ch(len204), k=5, dil=1, pad=4 ----
    {
        const int c0 = cgw * 8;
        const int t0 = lane * 4;        // 51 t-groups cover 204 exactly
        if (lane < 51) {
            float acc[8][4];
            #pragma unroll
            for (int cc = 0; cc < 8; cc++) {
                const float bb = cb1[c0 + cc];
                #pragma unroll
                for (int t = 0; t < 4; t++) acc[cc][t] = bb;
            }
            #pragma unroll
            for (int i = 0; i < 6; i++) {
                float inv[8];
                #pragma unroll
                for (int u = 0; u < 2; u++) {
                    float4 q = *(const float4*)&sm[SX + i * SX_STRIDE + t0 + 4 * u];
                    inv[4*u+0]=q.x; inv[4*u+1]=q.y; inv[4*u+2]=q.z; inv[4*u+3]=q.w;
                }
                #pragma unroll
                for (int cc = 0; cc < 8; cc++) {
                    const float* wp = cw1 + ((c0 + cc) * 6 + i) * 5; // wave-uniform -> s_load
                    const float w0=wp[0], w1=wp[1], w2=wp[2], w3=wp[3], w4=wp[4];
                    #pragma unroll
                    for (int t = 0; t < 4; t++)
                        acc[cc][t] += w0*inv[t] + w1*inv[t+1] + w2*inv[t+2]
                                    + w3*inv[t+3] + w4*inv[t+4];
                }
            }
            #pragma unroll
            for (int cc = 0; cc < 8; cc++) {
                float4 st;
                st.x = gelu_f(acc[cc][0]); st.y = gelu_f(acc[cc][1]);
                st.z = gelu_f(acc[cc][2]); st.w = gelu_f(acc[cc][3]);
                *(float4*)&sm[SH1 + (c0 + cc) * SH1_STRIDE + 4 + t0] = st;
            }
        }
    }
    __syncthreads();

    // ---- conv2: 32ch(len204) -> 32ch(len200), k=5, dil=3, pad=4 ----
    {
        const int c0 = cgw * 8;
        const int t0 = lane * 4;        // 50 t-groups cover 200 exactly
        if (lane < 50) {
            float acc[8][4];
            #pragma unroll
            for (int cc = 0; cc < 8; cc++) {
                const float bb = cb2[c0 + cc];
                #pragma unroll
                for (int t = 0; t < 4; t++) acc[cc][t] = bb;
            }
            for (int i = 0; i < 32; i++) {
                float inv[20];
                #pragma unroll
                for (int u = 0; u < 5; u++) {
                    float4 q = *(const float4*)&sm[SH1 + i * SH1_STRIDE + t0 + 4 * u];
                    inv[4*u+0]=q.x; inv[4*u+1]=q.y; inv[4*u+2]=q.z; inv[4*u+3]=q.w;
                }
                #pragma unroll
                for (int cc = 0; cc < 8; cc++) {
                    const float* wp = cw2 + ((c0 + cc) * 32 + i) * 5;
                    const float w0=wp[0], w1=wp[1], w2=wp[2], w3=wp[3], w4=wp[4];
                    #pragma unroll
                    for (int t = 0; t < 4; t++)
                        acc[cc][t] += w0*inv[t] + w1*inv[t+3] + w2*inv[t+6]
                                    + w3*inv[t+9] + w4*inv[t+12];
                }
            }
            #pragma unroll
            for (int cc = 0; cc < 8; cc++) {
                float4 st;
                st.x = gelu_f(acc[cc][0]); st.y = gelu_f(acc[cc][1]);
                st.z = gelu_f(acc[cc][2]); st.w = gelu_f(acc[cc][3]);
                *(float4*)&sm[SH2 + (c0 + cc) * SH2_STRIDE + 4 + t0] = st;
            }
        }
    }
    __syncthreads();

    // ---- conv3: 32ch(len200) -> 32ch(len196), k=5, dil=3, pad=4 (out -> SH1) ----
    {
        // h3 reuses SH1: stale h1 tail [200,204) must become zero padding for conv4.
        if (tid < 128) sm[SH1 + (tid >> 2) * SH1_STRIDE + 200 + (tid & 3)] = 0.0f;
        const int c0 = cgw * 8;
        const int t0 = lane * 4;        // 49 t-groups cover 196 exactly
        if (lane < 49) {
            float acc[8][4];
            #pragma unroll
            for (int cc = 0; cc < 8; cc++) {
                const float bb = cb3[c0 + cc];
                #pragma unroll
                for (int t = 0; t < 4; t++) acc[cc][t] = bb;
            }
            for (int i = 0; i < 32; i++) {
                float inv[20];
                #pragma unroll
                for (int u = 0; u < 5; u++) {
                    float4 q = *(const float4*)&sm[SH2 + i * SH2_STRIDE + t0 + 4 * u];
                    inv[4*u+0]=q.x; inv[4*u+1]=q.y; inv[4*u+2]=q.z; inv[4*u+3]=q.w;
                }
                #pragma unroll
                for (int cc = 0; cc < 8; cc++) {
                    const float* wp = cw3 + ((c0 + cc) * 32 + i) * 5;
                    const float w0=wp[0], w1=wp[1], w2=wp[2], w3=wp[3], w4=wp[4];
                    #pragma unroll
                    for (int t = 0; t < 4; t++)
                        acc[cc][t] += w0*inv[t] + w1*inv[t+3] + w2*inv[t+6]
                                    + w3*inv[t+9] + w4*inv[t+12];
                }
            }
            #pragma unroll
            for (int cc = 0; cc < 8; cc++) {
                float4 st;
                st.x = gelu_f(acc[cc][0]); st.y = gelu_f(acc[cc][1]);
                st.z = gelu_f(acc[cc][2]); st.w = gelu_f(acc[cc][3]);
                *(float4*)&sm[SH1 + (c0 + cc) * SH1_STRIDE + 4 + t0] = st;
            }
        }
    }
    __syncthreads();

    // ---- conv4: 32ch(len196) -> 1ch(len192), k=5, dil=3, pad=4 ----
    if (tid < 192) {
        float acc = cb4[0];
        for (int i = 0; i < 32; i++) {
            const float* wp = cw4 + i * 5;            // uniform -> s_load
            #pragma unroll
            for (int k = 0; k < 5; k++)
                acc = fmaf(wp[k], sm[SH1 + i * SH1_STRIDE + tid + 3 * k], acc);
        }
        sm[SF + tid] = gelu_f(acc);
    }
    __syncthreads();

    // ---- linear1: 192 -> 50, gelu ----
    if (tid < 50) {
        float acc = lb1[tid];
        const float* wr = lw1 + tid * 192;
        for (int j = 0; j < 192; j += 4) {
            float4 w = *(const float4*)&wr[j];
            float4 f = *(const float4*)&sm[SF + j];
            acc += w.x*f.x + w.y*f.y + w.z*f.z + w.w*f.w;
        }
        sm[SZ1 + tid] = gelu_f(acc);
    }
    __syncthreads();

    // ---- linear2: 50 -> 50, gelu ----
    if (tid < 50) {
        float acc = lb2[tid];
        const float* wr = lw2 + tid * 50;
        for (int j = 0; j < 50; j++) acc = fmaf(wr[j], sm[SZ1 + j], acc);
        sm[SZ2 + tid] = gelu_f(acc);
    }
    __syncthreads();

    // ---- linear3: 50 -> 15, *100 ----
    if (tid < 15) {
        float acc = lb3[tid];
        const float* wr = lw3 + tid * 50;
        for (int j = 0; j < 50; j++) acc = fmaf(wr[j], sm[SZ2 + j], acc);
        sm[SZV + tid] = acc * 100.0f;
    }
    __syncthreads();

    // ---- tail outputs z[9:15] ----
    if (tid >= 9 && tid < 15) out[(size_t)b * 15 + tid] = sm[SZV + tid];

    // ---- 3x3 SVD -> nearest rotation (thread 0) ----
    if (tid == 0) {
        const float A00 = sm[SZV+0], A01 = sm[SZV+1], A02 = sm[SZV+2];
        const float A10 = sm[SZV+3], A11 = sm[SZV+4], A12 = sm[SZV+5];
        const float A20 = sm[SZV+6], A21 = sm[SZV+7], A22 = sm[SZV+8];
        // S = A^T A
        float S00 = A00*A00 + A10*A10 + A20*A20;
        float S01 = A00*A01 + A10*A11 + A20*A21;
        float S02 = A00*A02 + A10*A12 + A20*A22;
        float S11 = A01*A01 + A11*A11 + A21*A21;
        float S12 = A01*A02 + A11*A12 + A21*A22;
        float S22 = A02*A02 + A12*A12 + A22*A22;
        // V starts as identity; Jacobi rotations keep det(V) = +1
        float V00=1.f, V01=0.f, V02=0.f;
        float V10=0.f, V11=1.f, V12=0.f;
        float V20=0.f, V21=0.f, V22=1.f;
        #pragma unroll
        for (int sweep = 0; sweep < 8; sweep++) {
            JROT(S00, S11, S01, S02, S12, V00, V01, V10, V11, V20, V21)
            JROT(S00, S22, S02, S01, S12, V00, V02, V10, V12, V20, V22)
            JROT(S11, S22, S12, S01, S02, V01, V02, V11, V12, V21, V22)
        }
        // sort eigenpairs descending; track permutation parity to keep det(V)=+1
        float e0 = S00, e1 = S11, e2 = S22;
        float va0=V00, va1=V10, va2=V20;   // column 0
        float vb0=V01, vb1=V11, vb2=V21;   // column 1
        float vc0=V02, vc1=V12, vc2=V22;   // column 2
        float sgn = 1.0f, t;
        if (e0 < e1) { t=e0;e0=e1;e1=t; t=va0;va0=vb0;vb0=t; t=va1;va1=vb1;vb1=t; t=va2;va2=vb2;vb2=t; sgn=-sgn; }
        if (e1 < e2) { t=e1;e1=e2;e2=t; t=vb0;vb0=vc0;vc0=t; t=vb1;vb1=vc1;vc1=t; t=vb2;vb2=vc2;vc2=t; sgn=-sgn; }
        if (e0 < e1) { t=e0;e0=e1;e1=t; t=va0;va0=vb0;vb0=t; t=va1;va1=vb1;vb1=t; t=va2;va2=vb2;vb2=t; sgn=-sgn; }
        vc0 *= sgn; vc1 *= sgn; vc2 *= sgn;
        // u1 = normalize(A v1)
        float u10 = A00*va0 + A01*va1 + A02*va2;
        float u11 = A10*va0 + A11*va1 + A12*va2;
        float u12 = A20*va0 + A21*va1 + A22*va2;
        float n1 = sqrtf(u10*u10 + u11*u11 + u12*u12);
        float rn1 = (n1 > 1e-20f) ? 1.0f / n1 : 0.0f;
        u10 *= rn1; u11 *= rn1; u12 *= rn1;
        // u2 = normalize(A v2 orthogonalized against u1)
        float u20 = A00*vb0 + A01*vb1 + A02*vb2;
        float u21 = A10*vb0 + A11*vb1 + A12*vb2;
        float u22 = A20*vb0 + A21*vb1 + A22*vb2;
        float d12 = u20*u10 + u21*u11 + u22*u12;
        u20 -= d12*u10; u21 -= d12*u11; u22 -= d12*u12;
        float n2 = sqrtf(u20*u20 + u21*u21 + u22*u22);
        float rn2 = (n2 > 1e-20f) ? 1.0f / n2 : 0.0f;
        u20 *= rn2; u21 *= rn2; u22 *= rn2;
        // u3 = u1 x u2  (encodes the det-sign flip; robust at sigma3 -> 0)
        float u30 = u11*u22 - u12*u21;
        float u31 = u12*u20 - u10*u22;
        float u32 = u10*u21 - u11*u20;
        // R[r][c] = u1[r]v1[c] + u2[r]v2[c] + u3[r]v3[c]
        float* ob = out + (size_t)b * 15;
        ob[0] = u10*va0 + u20*vb0 + u30*vc0;
        ob[1] = u10*va1 + u20*vb1 + u30*vc1;
        ob[2] = u10*va2 + u20*vb2 + u30*vc2;
        ob[3] = u11*va0 + u21*vb0 + u31*vc0;
        ob[4] = u11*va1 + u21*vb1 + u31*vc1;
        ob[5] = u11*va2 + u21*vb2 + u31*vc2;
        ob[6] = u12*va0 + u22*vb0 + u32*vc0;
        ob[7] = u12*va1 + u22*vb1 + u32*vc1;
        ob[8] = u12*va2 + u22*vb2 + u32*vc2;
    }
}

extern "C" void kernel_launch(void* const* d_in, const int* in_sizes, int n_in,
                              void* d_out, int out_size, void* d_ws, size_t ws_size,
                              hipStream_t stream) {
    (void)n_in; (void)out_size; (void)d_ws; (void)ws_size;
    const float* x     = (const float*)d_in[0];
    const float* calib = (const float*)d_in[1];
    const float* biasv = (const float*)d_in[2];
    const float* cw1   = (const float*)d_in[3];
    const float* cb1   = (const float*)d_in[4];
    const float* cw2   = (const float*)d_in[5];
    const float* cb2   = (const float*)d_in[6];
    const float* cw3   = (const float*)d_in[7];
    const float* cb3   = (const float*)d_in[8];
    const float* cw4   = (const float*)d_in[9];
    const float* cb4   = (const float*)d_in[10];
    const float* lw1   = (const float*)d_in[11];
    const float* lb1   = (const float*)d_in[12];
    const float* lw2   = (const float*)d_in[13];
    const float* lb2   = (const float*)d_in[14];
    const float* lw3   = (const float*)d_in[15];
    const float* lb3   = (const float*)d_in[16];
    float* out = (float*)d_out;
    const int B = in_sizes[0] / 1400;
    hipLaunchKernelGGL(rminet_kernel, dim3(B), dim3(NTHREADS), 0, stream,
                       x, calib, biasv, cw1, cb1, cw2, cb2, cw3, cb3, cw4, cb4,
                       lw1, lb1, lw2, lb2, lw3, lb3, out);
}

// Round 2
// 882.047 us; speedup vs baseline: 1.2662x; 1.2662x over previous
//
#include <hip/hip_runtime.h>
#include <math.h>

#define NTHREADS 256

// ---- LDS layout, byte-addressed. h-activations stored as bf16 (RNE) with
// zero-padded rows: left pad 4 values, row stride 212 values (424 B, 8B-
// aligned) so conv2/3 read exactly 16 contiguous bf16 = 4x ds_read_b64 at
// byte offset 8*lane (conflict-free: 16-lane phase covers all 32 banks).
// Total 33,472 B -> 4 blocks/CU (16 waves, ~50% occupancy) vs 62 KB/2 blocks.
#define SXF        0          // float idx: 6 rows x stride 208 f32, data [4,204)
#define SXF_STRIDE 208
#define SH1H       2496       // ushort idx (byte 4992): 32 x stride 212 bf16
#define SH2H       9280       // ushort idx (byte 18560): 32 x stride 212 bf16
#define SHSTRIDE   212
#define SFF        8032       // float idx (byte 32128): 192 f32
#define SZ1F       8224       // float idx: 50 (pad 64)
#define SZ2F       8288
#define SZVF       8352       // 15 (pad 16)
#define SMEM_BYTES 33472

__device__ __forceinline__ float gelu_f(float v) {
    return 0.5f * v * (1.0f + erff(v * 0.70710678118654752f));
}

// f32 -> bf16 round-to-nearest-even (inputs are finite; no NaN handling)
__device__ __forceinline__ unsigned f2bf(float f) {
    unsigned u = __float_as_uint(f);
    return (u + 0x7FFFu + ((u >> 16) & 1u)) >> 16;
}
// unpack uint32 holding 2 bf16 (little-endian) -> 2 f32
#define UNPK2(q, d0, d1) { d0 = __uint_as_float((q) << 16); d1 = __uint_as_float((q) & 0xffff0000u); }

// One Jacobi rotation in plane (p,q); all named scalars.
#define JROT(Spp, Sqq, Spq, Sxp, Sxq, Vp0, Vq0, Vp1, Vq1, Vp2, Vq2)          \
    if (fabsf(Spq) > 1e-18f) {                                               \
        float tau = (Sqq - Spp) / (2.0f * Spq);                              \
        float tj = copysignf(1.0f, tau) / (fabsf(tau) + sqrtf(1.0f + tau*tau)); \
        float cj = 1.0f / sqrtf(1.0f + tj*tj);                               \
        float sj = tj * cj;                                                  \
        Spp -= tj * Spq; Sqq += tj * Spq; Spq = 0.0f;                        \
        float tmp0 = Sxp; Sxp = cj*tmp0 - sj*Sxq; Sxq = sj*tmp0 + cj*Sxq;    \
        float tv;                                                            \
        tv = Vp0; Vp0 = cj*tv - sj*Vq0; Vq0 = sj*tv + cj*Vq0;                \
        tv = Vp1; Vp1 = cj*tv - sj*Vq1; Vq1 = sj*tv + cj*Vq1;                \
        tv = Vp2; Vp2 = cj*tv - sj*Vq2; Vq2 = sj*tv + cj*Vq2;                \
    }

__global__ void __launch_bounds__(NTHREADS, 4)
rminet_kernel(const float* __restrict__ x,
              const float* __restrict__ calib,
              const float* __restrict__ biasv,
              const float* __restrict__ cw1, const float* __restrict__ cb1,
              const float* __restrict__ cw2, const float* __restrict__ cb2,
              const float* __restrict__ cw3, const float* __restrict__ cb3,
              const float* __restrict__ cw4, const float* __restrict__ cb4,
              const float* __restrict__ lw1, const float* __restrict__ lb1,
              const float* __restrict__ lw2, const float* __restrict__ lb2,
              const float* __restrict__ lw3, const float* __restrict__ lb3,
              float* __restrict__ out)
{
    __shared__ __align__(16) unsigned char smb[SMEM_BYTES];
    float*          smf = (float*)smb;
    unsigned short* smh = (unsigned short*)smb;

    const int tid  = threadIdx.x;
    const int b    = blockIdx.x;
    const int lane = tid & 63;
    const int cgw  = __builtin_amdgcn_readfirstlane(tid >> 6); // wave-uniform 0..3

    // ---- zero all LDS (establishes the zero pads) ----
    {
        uint4* p = (uint4*)smb;
        for (int i = tid; i < SMEM_BYTES / 16; i += NTHREADS)
            p[i] = make_uint4(0u, 0u, 0u, 0u);
    }
    __syncthreads();

    // ---- load imu = x[b,1:7,:] (1200 contiguous f32) into SX ----
    const float* xb = x + (size_t)b * 1400 + 200;
    for (int idx = tid; idx < 1200; idx += NTHREADS) {
        int row = idx / 200;
        int col = idx - row * 200;
        smf[SXF + row * SXF_STRIDE + 4 + col] = xb[idx];
    }
    __syncthreads();

    // ---- calibration (M = I + calib) + bias + normalize, in place ----
    if (tid < 200) {
        float v[6];
        #pragma unroll
        for (int j = 0; j < 6; j++) v[j] = smf[SXF + j * SXF_STRIDE + 4 + tid];
        const float MEANS[6]  = {0.042766f, 0.0081577f, -0.015818f, 9.2993f, -0.087913f, -3.3231f};
        const float INVSTD[6] = {1.f/0.4142f, 1.f/0.3522f, 1.f/0.2881f, 1.f/1.474f, 1.f/0.6553f, 1.f/0.8728f};
        #pragma unroll
        for (int i = 0; i < 6; i++) {
            float acc = biasv[i];
            #pragma unroll
            for (int j = 0; j < 6; j++) {
                float m = calib[i * 6 + j] + ((i == j) ? 1.0f : 0.0f);
                acc = fmaf(m, v[j], acc);
            }
            smf[SXF + i * SXF_STRIDE + 4 + tid] = (acc - MEANS[i]) * INVSTD[i];
        }
    }
    __syncthreads();

    // ---- conv1: 6ch(200) -> 32ch(204), k=5, dil=1, pad=4; out bf16 -> SH1 ----
    {
        const int c0 = cgw * 8;
        const int t0 = lane * 4;            // 51 groups cover 204
        if (lane < 51) {
            float acc[8][4];
            #pragma unroll
            for (int cc = 0; cc < 8; cc++) {
                const float bb = cb1[c0 + cc];
                #pragma unroll
                for (int t = 0; t < 4; t++) acc[cc][t] = bb;
            }
            #pragma unroll
            for (int i = 0; i < 6; i++) {
                float inv[8];
                #pragma unroll
                for (int u = 0; u < 2; u++) {
                    float4 q = *(const float4*)&smf[SXF + i * SXF_STRIDE + t0 + 4 * u];
                    inv[4*u+0]=q.x; inv[4*u+1]=q.y; inv[4*u+2]=q.z; inv[4*u+3]=q.w;
                }
                #pragma unroll
                for (int cc = 0; cc < 8; cc++) {
                    const float* wp = cw1 + ((c0 + cc) * 6 + i) * 5; // wave-uniform -> s_load
                    const float w0=wp[0], w1=wp[1], w2=wp[2], w3=wp[3], w4=wp[4];
                    #pragma unroll
                    for (int t = 0; t < 4; t++)
                        acc[cc][t] += w0*inv[t] + w1*inv[t+1] + w2*inv[t+2]
                                    + w3*inv[t+3] + w4*inv[t+4];
                }
            }
            #pragma unroll
            for (int cc = 0; cc < 8; cc++) {
                unsigned p0 = f2bf(gelu_f(acc[cc][0])) | (f2bf(gelu_f(acc[cc][1])) << 16);
                unsigned p1 = f2bf(gelu_f(acc[cc][2])) | (f2bf(gelu_f(acc[cc][3])) << 16);
                *(uint2*)&smh[SH1H + (c0 + cc) * SHSTRIDE + 4 + t0] = make_uint2(p0, p1);
            }
        }
    }
    __syncthreads();

    // ---- conv2: 32ch(204) -> 32ch(200), k=5, dil=3, pad=4; bf16 in/out ----
    {
        const int c0 = cgw * 8;
        const int t0 = lane * 4;            // 50 groups cover 200
        if (lane < 50) {
            float acc[8][4];
            #pragma unroll
            for (int cc = 0; cc < 8; cc++) {
                const float bb = cb2[c0 + cc];
                #pragma unroll
                for (int t = 0; t < 4; t++) acc[cc][t] = bb;
            }
            for (int i = 0; i < 32; i++) {
                // 16 contiguous bf16 starting at stored idx t0 (byte 8*lane)
                const unsigned short* r = &smh[SH1H + i * SHSTRIDE + t0];
                float inv[16];
                #pragma unroll
                for (int u = 0; u < 4; u++) {
                    uint2 q = *(const uint2*)(r + 4 * u);
                    UNPK2(q.x, inv[4*u+0], inv[4*u+1]);
                    UNPK2(q.y, inv[4*u+2], inv[4*u+3]);
                }
                #pragma unroll
                for (int cc = 0; cc < 8; cc++) {
                    const float* wp = cw2 + ((c0 + cc) * 32 + i) * 5;
                    const float w0=wp[0], w1=wp[1], w2=wp[2], w3=wp[3], w4=wp[4];
                    #pragma unroll
                    for (int t = 0; t < 4; t++)
                        acc[cc][t] += w0*inv[t] + w1*inv[t+3] + w2*inv[t+6]
                                    + w3*inv[t+9] + w4*inv[t+12];
                }
            }
            #pragma unroll
            for (int cc = 0; cc < 8; cc++) {
                unsigned p0 = f2bf(gelu_f(acc[cc][0])) | (f2bf(gelu_f(acc[cc][1])) << 16);
                unsigned p1 = f2bf(gelu_f(acc[cc][2])) | (f2bf(gelu_f(acc[cc][3])) << 16);
                *(uint2*)&smh[SH2H + (c0 + cc) * SHSTRIDE + 4 + t0] = make_uint2(p0, p1);
            }
        }
    }
    __syncthreads();

    // ---- conv3: 32ch(200) -> 32ch(196), k=5, dil=3, pad=4; out -> SH1 ----
    {
        // h3 reuses SH1: zero stale h1 at stored idx [200,212) (bytes 400..424)
        // per row; disjoint from h3 writes (idx <= 199), so no intra-stage race.
        if (tid < 96) {
            int row = tid / 3, t3 = tid - row * 3;
            *(uint2*)&smh[SH1H + row * SHSTRIDE + 200 + 4 * t3] = make_uint2(0u, 0u);
        }
        const int c0 = cgw * 8;
        const int t0 = lane * 4;            // 49 groups cover 196
        if (lane < 49) {
            float acc[8][4];
            #pragma unroll
            for (int cc = 0; cc < 8; cc++) {
                const float bb = cb3[c0 + cc];
                #pragma unroll
                for (int t = 0; t < 4; t++) acc[cc][t] = bb;
            }
            for (int i = 0; i < 32; i++) {
                const unsigned short* r = &smh[SH2H + i * SHSTRIDE + t0];
                float inv[16];
                #pragma unroll
                for (int u = 0; u < 4; u++) {
                    uint2 q = *(const uint2*)(r + 4 * u);
                    UNPK2(q.x, inv[4*u+0], inv[4*u+1]);
                    UNPK2(q.y, inv[4*u+2], inv[4*u+3]);
                }
                #pragma unroll
                for (int cc = 0; cc < 8; cc++) {
                    const float* wp = cw3 + ((c0 + cc) * 32 + i) * 5;
                    const float w0=wp[0], w1=wp[1], w2=wp[2], w3=wp[3], w4=wp[4];
                    #pragma unroll
                    for (int t = 0; t < 4; t++)
                        acc[cc][t] += w0*inv[t] + w1*inv[t+3] + w2*inv[t+6]
                                    + w3*inv[t+9] + w4*inv[t+12];
                }
            }
            #pragma unroll
            for (int cc = 0; cc < 8; cc++) {
                unsigned p0 = f2bf(gelu_f(acc[cc][0])) | (f2bf(gelu_f(acc[cc][1])) << 16);
                unsigned p1 = f2bf(gelu_f(acc[cc][2])) | (f2bf(gelu_f(acc[cc][3])) << 16);
                *(uint2*)&smh[SH1H + (c0 + cc) * SHSTRIDE + 4 + t0] = make_uint2(p0, p1);
            }
        }
    }
    __syncthreads();

    // ---- conv4: 32ch(196) -> 1ch(192), k=5, dil=3, pad=4 ----
    if (tid < 192) {
        float acc = cb4[0];
        for (int i = 0; i < 32; i++) {
            const float* wp = cw4 + i * 5;            // uniform -> s_load
            const unsigned short* r = &smh[SH1H + i * SHSTRIDE + tid];
            #pragma unroll
            for (int k = 0; k < 5; k++) {
                float hv = __uint_as_float(((unsigned)r[3 * k]) << 16);
                acc = fmaf(wp[k], hv, acc);
            }
        }
        smf[SFF + tid] = gelu_f(acc);
    }
    __syncthreads();

    // ---- linear1: 192 -> 50, gelu ----
    if (tid < 50) {
        float acc = lb1[tid];
        const float* wr = lw1 + tid * 192;
        for (int j = 0; j < 192; j += 4) {
            float4 w = *(const float4*)&wr[j];
            float4 f = *(const float4*)&smf[SFF + j];
            acc += w.x*f.x + w.y*f.y + w.z*f.z + w.w*f.w;
        }
        smf[SZ1F + tid] = gelu_f(acc);
    }
    __syncthreads();

    // ---- linear2: 50 -> 50, gelu ----
    if (tid < 50) {
        float acc = lb2[tid];
        const float* wr = lw2 + tid * 50;
        for (int j = 0; j < 50; j++) acc = fmaf(wr[j], smf[SZ1F + j], acc);
        smf[SZ2F + tid] = gelu_f(acc);
    }
    __syncthreads();

    // ---- linear3: 50 -> 15, *100 ----
    if (tid < 15) {
        float acc = lb3[tid];
        const float* wr = lw3 + tid * 50;
        for (int j = 0; j < 50; j++) acc = fmaf(wr[j], smf[SZ2F + j], acc);
        smf[SZVF + tid] = acc * 100.0f;
    }
    __syncthreads();

    // ---- tail outputs z[9:15] ----
    if (tid >= 9 && tid < 15) out[(size_t)b * 15 + tid] = smf[SZVF + tid];

    // ---- 3x3 SVD -> nearest rotation (thread 0) ----
    if (tid == 0) {
        const float A00 = smf[SZVF+0], A01 = smf[SZVF+1], A02 = smf[SZVF+2];
        const float A10 = smf[SZVF+3], A11 = smf[SZVF+4], A12 = smf[SZVF+5];
        const float A20 = smf[SZVF+6], A21 = smf[SZVF+7], A22 = smf[SZVF+8];
        float S00 = A00*A00 + A10*A10 + A20*A20;
        float S01 = A00*A01 + A10*A11 + A20*A21;
        float S02 = A00*A02 + A10*A12 + A20*A22;
        float S11 = A01*A01 + A11*A11 + A21*A21;
        float S12 = A01*A02 + A11*A12 + A21*A22;
        float S22 = A02*A02 + A12*A12 + A22*A22;
        float V00=1.f, V01=0.f, V02=0.f;
        float V10=0.f, V11=1.f, V12=0.f;
        float V20=0.f, V21=0.f, V22=1.f;
        #pragma unroll
        for (int sweep = 0; sweep < 8; sweep++) {
            JROT(S00, S11, S01, S02, S12, V00, V01, V10, V11, V20, V21)
            JROT(S00, S22, S02, S01, S12, V00, V02, V10, V12, V20, V22)
            JROT(S11, S22, S12, S01, S02, V01, V02, V11, V12, V21, V22)
        }
        float e0 = S00, e1 = S11, e2 = S22;
        float va0=V00, va1=V10, va2=V20;
        float vb0=V01, vb1=V11, vb2=V21;
        float vc0=V02, vc1=V12, vc2=V22;
        float sgn = 1.0f, t;
        if (e0 < e1) { t=e0;e0=e1;e1=t; t=va0;va0=vb0;vb0=t; t=va1;va1=vb1;vb1=t; t=va2;va2=vb2;vb2=t; sgn=-sgn; }
        if (e1 < e2) { t=e1;e1=e2;e2=t; t=vb0;vb0=vc0;vc0=t; t=vb1;vb1=vc1;vc1=t; t=vb2;vb2=vc2;vc2=t; sgn=-sgn; }
        if (e0 < e1) { t=e0;e0=e1;e1=t; t=va0;va0=vb0;vb0=t; t=va1;va1=vb1;vb1=t; t=va2;va2=vb2;vb2=t; sgn=-sgn; }
        vc0 *= sgn; vc1 *= sgn; vc2 *= sgn;
        float u10 = A00*va0 + A01*va1 + A02*va2;
        float u11 = A10*va0 + A11*va1 + A12*va2;
        float u12 = A20*va0 + A21*va1 + A22*va2;
        float n1 = sqrtf(u10*u10 + u11*u11 + u12*u12);
        float rn1 = (n1 > 1e-20f) ? 1.0f / n1 : 0.0f;
        u10 *= rn1; u11 *= rn1; u12 *= rn1;
        float u20 = A00*vb0 + A01*vb1 + A02*vb2;
        float u21 = A10*vb0 + A11*vb1 + A12*vb2;
        float u22 = A20*vb0 + A21*vb1 + A22*vb2;
        float d12 = u20*u10 + u21*u11 + u22*u12;
        u20 -= d12*u10; u21 -= d12*u11; u22 -= d12*u12;
        float n2 = sqrtf(u20*u20 + u21*u21 + u22*u22);
        float rn2 = (n2 > 1e-20f) ? 1.0f / n2 : 0.0f;
        u20 *= rn2; u21 *= rn2; u22 *= rn2;
        float u30 = u11*u22 - u12*u21;
        float u31 = u12*u20 - u10*u22;
        float u32 = u10*u21 - u11*u20;
        float* ob = out + (size_t)b * 15;
        ob[0] = u10*va0 + u20*vb0 + u30*vc0;
        ob[1] = u10*va1 + u20*vb1 + u30*vc1;
        ob[2] = u10*va2 + u20*vb2 + u30*vc2;
        ob[3] = u11*va0 + u21*vb0 + u31*vc0;
        ob[4] = u11*va1 + u21*vb1 + u31*vc1;
        ob[5] = u11*va2 + u21*vb2 + u31*vc2;
        ob[6] = u12*va0 + u22*vb0 + u32*vc0;
        ob[7] = u12*va1 + u22*vb1 + u32*vc1;
        ob[8] = u12*va2 + u22*vb2 + u32*vc2;
    }
}

extern "C" void kernel_launch(void* const* d_in, const int* in_sizes, int n_in,
                              void* d_out, int out_size, void* d_ws, size_t ws_size,
                              hipStream_t stream) {
    (void)n_in; (void)out_size; (void)d_ws; (void)ws_size;
    const float* x     = (const float*)d_in[0];
    const float* calib = (const float*)d_in[1];
    const float* biasv = (const float*)d_in[2];
    const float* cw1   = (const float*)d_in[3];
    const float* cb1   = (const float*)d_in[4];
    const float* cw2   = (const float*)d_in[5];
    const float* cb2   = (const float*)d_in[6];
    const float* cw3   = (const float*)d_in[7];
    const float* cb3   = (const float*)d_in[8];
    const float* cw4   = (const float*)d_in[9];
    const float* cb4   = (const float*)d_in[10];
    const float* lw1   = (const float*)d_in[11];
    const float* lb1   = (const float*)d_in[12];
    const float* lw2   = (const float*)d_in[13];
    const float* lb2   = (const float*)d_in[14];
    const float* lw3   = (const float*)d_in[15];
    const float* lb3   = (const float*)d_in[16];
    float* out = (float*)d_out;
    const int B = in_sizes[0] / 1400;
    hipLaunchKernelGGL(rminet_kernel, dim3(B), dim3(NTHREADS), 0, stream,
                       x, calib, biasv, cw1, cb1, cw2, cb2, cw3, cb3, cw4, cb4,
                       lw1, lb1, lw2, lb2, lw3, lb3, out);
}

// Round 3
// 276.172 us; speedup vs baseline: 4.0442x; 3.1938x over previous
//
#include <hip/hip_runtime.h>
#include <math.h>

#define NTHREADS 256
typedef __attribute__((ext_vector_type(8))) short short8;
typedef __attribute__((ext_vector_type(4))) float f32x4;
typedef unsigned short ushort_t;

// ---- LDS layout (halfword indices). Two time-major activation buffers:
// hT[row=t_padded][ch], 212 rows x stride 40 bf16 (80 B: 16B-aligned rows).
// B-fragment for mfma_16x16x32_bf16 = 8 contiguous channels at one row
// = one ds_read_b128. Row addresses stride 80 B = 20 dwords -> even bank
// spread. Tail scalars (f, z1, z2, zv) live as fp32 after the buffers.
#define HA    0          // bufA (h1, h3)
#define HB    8480       // bufB (im2col BT1, then h2)
#define HSTR  40
// float indices (float* view): tail starts at halfword 16960 = float 8480
#define SF    8480       // 192 floats
#define SZ1   8672       // 50 (pad 64)
#define SZ2   8736
#define SZV   8800       // 15 (pad 16)
#define SMEM_HW 17632    // 35,264 B -> 4 blocks/CU

// ws (d_ws) fragment bases in halfwords; each A-frag = 64 lanes x 8 bf16 = 512 hw
#define WSF_C1 0         // 2 frags  (conv1, taps folded into K=30)
#define WSF_C2 1024      // 10 frags (conv2: 5 taps x 2 Mtiles)
#define WSF_C3 6144      // 10 frags (conv3)

__device__ __forceinline__ unsigned f2bf(float f) {
    unsigned u = __float_as_uint(f);
    return (u + 0x7FFFu + ((u >> 16) & 1u)) >> 16;
}

// fast GELU: tanh form via exp2; max abs err vs exact ~3e-4 (below bf16 noise)
__device__ __forceinline__ float gelu_fast(float x) {
    float x2 = x * x;
    float u  = x * fmaf(0.044715f, x2, 1.0f);
    float e  = __builtin_amdgcn_exp2f(u * 2.3022082f);   // 2*0.79788456*log2(e)
    float r  = __builtin_amdgcn_rcpf(e + 1.0f);
    float th = fmaf(-2.0f, r, 1.0f);
    float hx = 0.5f * x;
    return fmaf(hx, th, hx);
}

__device__ __forceinline__ float gelu_exact(float v) {
    return 0.5f * v * (1.0f + erff(v * 0.70710678118654752f));
}

#define JROT(Spp, Sqq, Spq, Sxp, Sxq, Vp0, Vq0, Vp1, Vq1, Vp2, Vq2)          \
    if (fabsf(Spq) > 1e-18f) {                                               \
        float tau = (Sqq - Spp) / (2.0f * Spq);                              \
        float tj = copysignf(1.0f, tau) / (fabsf(tau) + sqrtf(1.0f + tau*tau)); \
        float cj = 1.0f / sqrtf(1.0f + tj*tj);                               \
        float sj = tj * cj;                                                  \
        Spp -= tj * Spq; Sqq += tj * Spq; Spq = 0.0f;                        \
        float tmp0 = Sxp; Sxp = cj*tmp0 - sj*Sxq; Sxq = sj*tmp0 + cj*Sxq;    \
        float tv;                                                            \
        tv = Vp0; Vp0 = cj*tv - sj*Vq0; Vq0 = sj*tv + cj*Vq0;                \
        tv = Vp1; Vp1 = cj*tv - sj*Vq1; Vq1 = sj*tv + cj*Vq1;                \
        tv = Vp2; Vp2 = cj*tv - sj*Vq2; Vq2 = sj*tv + cj*Vq2;                \
    }

// ---- prep: repack conv weights into MFMA A-fragment lane order (bf16) ----
// A-layout (verified m120 note): lane l holds A[m = l&15][k = (l>>4)*8 + j].
// frag(fid): 64 lanes x 8 values at ws[fid*512 + l*8 + j].
__global__ void prep_kernel(const float* __restrict__ cw1,
                            const float* __restrict__ cw2,
                            const float* __restrict__ cw3,
                            ushort_t* __restrict__ ws)
{
    const int fid = blockIdx.x;          // 0..21
    const int l = threadIdx.x >> 3;      // lane 0..63
    const int j = threadIdx.x & 7;
    const int lo = l & 15, q = l >> 4;
    float v;
    if (fid < 2) {                       // conv1: A[c][kk], kk = i*5+tap (K=30, pad 0)
        int c = fid * 16 + lo, kk = q * 8 + j;
        v = (kk < 30) ? cw1[c * 30 + kk] : 0.0f;
    } else if (fid < 12) {               // conv2: frag(tap, Mt)
        int f = fid - 2, tap = f >> 1, Mt = f & 1;
        int c = Mt * 16 + lo, i = q * 8 + j;
        v = cw2[(c * 32 + i) * 5 + tap];
    } else {                             // conv3
        int f = fid - 12, tap = f >> 1, Mt = f & 1;
        int c = Mt * 16 + lo, i = q * 8 + j;
        v = cw3[(c * 32 + i) * 5 + tap];
    }
    ws[fid * 512 + l * 8 + j] = (ushort_t)f2bf(v);
}

// ---- MFMA conv layer: out[c][n] = gelu(bias[c] + sum_tap,i W·hT[n+3tap][i])
// B-frag: B[k=i][n] <- src[n0+(lane&15)+3*tap][ (lane>>4)*8 .. +7 ]  (b128)
// C/D (m89): col n = lane&15, row m = (lane>>4)*4 + reg  -> store 4 consec
// channels as uint2 into dst[4+n][c].
template<int TAPS>
__device__ __forceinline__ void conv_mfma(
    const ushort_t* __restrict__ src, ushort_t* __restrict__ dst,
    const ushort_t* __restrict__ wsf, const float* __restrict__ bias,
    int Lout, int lane, int wave)
{
    const int lo16 = lane & 15;
    const int quad = lane >> 4;
    short8 A[TAPS][2];
    #pragma unroll
    for (int t = 0; t < TAPS; t++) {
        A[t][0] = *(const short8*)(wsf + (t * 2 + 0) * 512 + lane * 8);
        A[t][1] = *(const short8*)(wsf + (t * 2 + 1) * 512 + lane * 8);
    }
    f32x4 bias0, bias1;
    #pragma unroll
    for (int r = 0; r < 4; r++) {
        bias0[r] = bias[quad * 4 + r];
        bias1[r] = bias[16 + quad * 4 + r];
    }
    for (int tile = wave; tile < 13; tile += 4) {
        const int n0 = tile * 16;
        f32x4 acc0 = bias0, acc1 = bias1;
        #pragma unroll
        for (int t = 0; t < TAPS; t++) {
            int trow = n0 + lo16 + 3 * t;
            if (TAPS > 1 && trow > 211) trow = 211;   // garbage lanes: clamped (discarded)
            short8 B = *(const short8*)(src + trow * HSTR + quad * 8);
            acc0 = __builtin_amdgcn_mfma_f32_16x16x32_bf16(A[t][0], B, acc0, 0, 0, 0);
            acc1 = __builtin_amdgcn_mfma_f32_16x16x32_bf16(A[t][1], B, acc1, 0, 0, 0);
        }
        const int n = n0 + lo16;
        unsigned p00 = 0, p01 = 0, p10 = 0, p11 = 0;
        if (n < Lout) {
            p00 = f2bf(gelu_fast(acc0[0])) | (f2bf(gelu_fast(acc0[1])) << 16);
            p01 = f2bf(gelu_fast(acc0[2])) | (f2bf(gelu_fast(acc0[3])) << 16);
            p10 = f2bf(gelu_fast(acc1[0])) | (f2bf(gelu_fast(acc1[1])) << 16);
            p11 = f2bf(gelu_fast(acc1[2])) | (f2bf(gelu_fast(acc1[3])) << 16);
        }
        const int row = 4 + n;                        // zero-pads garbage rows
        *(uint2*)(dst + row * HSTR + quad * 4)      = make_uint2(p00, p01);
        *(uint2*)(dst + row * HSTR + 16 + quad * 4) = make_uint2(p10, p11);
    }
}

__global__ void __launch_bounds__(NTHREADS, 4)
rminet_kernel(const float* __restrict__ x,
              const float* __restrict__ calib,
              const float* __restrict__ biasv,
              const float* __restrict__ cb1, const float* __restrict__ cb2,
              const float* __restrict__ cb3,
              const float* __restrict__ cw4, const float* __restrict__ cb4,
              const float* __restrict__ lw1, const float* __restrict__ lb1,
              const float* __restrict__ lw2, const float* __restrict__ lb2,
              const float* __restrict__ lw3, const float* __restrict__ lb3,
              const ushort_t* __restrict__ wsp,
              float* __restrict__ out)
{
    __shared__ __align__(16) ushort_t smh[SMEM_HW];
    float* smf = (float*)smh;
    const int tid  = threadIdx.x;
    const int b    = blockIdx.x;
    const int lane = tid & 63;
    const int wave = __builtin_amdgcn_readfirstlane(tid >> 6);

    // ---- zero both activation buffers (16,960 hw = 2,120 uint4) ----
    {
        uint4* p = (uint4*)smh;
        for (int i = tid; i < 2120; i += NTHREADS) p[i] = make_uint4(0u,0u,0u,0u);
    }
    __syncthreads();

    // ---- calibrate+normalize xn (fp32 regs) and scatter im2col BT1 -> bufB
    // BT1[r][kk=i*5+tap] = xnp[i][r+tap]; value xn[i][t] lands at r=t+4-tap.
    if (tid < 200) {
        const float* xc = x + (size_t)b * 1400 + 200 + tid;
        float v[6];
        #pragma unroll
        for (int ch = 0; ch < 6; ch++) v[ch] = xc[ch * 200];
        const float MEANS[6]  = {0.042766f, 0.0081577f, -0.015818f, 9.2993f, -0.087913f, -3.3231f};
        const float INVSTD[6] = {1.f/0.4142f, 1.f/0.3522f, 1.f/0.2881f, 1.f/1.474f, 1.f/0.6553f, 1.f/0.8728f};
        #pragma unroll
        for (int i = 0; i < 6; i++) {
            float acc = biasv[i];
            #pragma unroll
            for (int jj = 0; jj < 6; jj++) {
                float m = calib[i * 6 + jj] + ((i == jj) ? 1.0f : 0.0f);
                acc = fmaf(m, v[jj], acc);
            }
            ushort_t hv = (ushort_t)f2bf((acc - MEANS[i]) * INVSTD[i]);
            #pragma unroll
            for (int tap = 0; tap < 5; tap++)
                smh[HB + (tid + 4 - tap) * HSTR + i * 5 + tap] = hv;
        }
    }
    __syncthreads();

    // ---- conv1 (MFMA, K=30 folded): BT1(bufB) -> h1(bufA), Lout=204 ----
    conv_mfma<1>(smh + HB, smh + HA, wsp + WSF_C1, cb1, 204, lane, wave);
    __syncthreads();

    // ---- conv2: h1(bufA) -> h2(bufB), Lout=200; also re-zero bufB rows 0..3
    // (stale BT1 data; conv2 stores only rows >= 4) ----
    if (tid < 80) *(unsigned*)(smh + HB + tid * 2) = 0u;
    conv_mfma<5>(smh + HA, smh + HB, wsp + WSF_C2, cb2, 200, lane, wave);
    __syncthreads();

    // ---- conv3: h2(bufB) -> h3(bufA), Lout=196 ----
    conv_mfma<5>(smh + HB, smh + HA, wsp + WSF_C3, cb3, 196, lane, wave);
    __syncthreads();

    // ---- conv4: 32ch -> 1ch, len 192 (scalar; reads hT rows, unpack bf16) ----
    if (tid < 192) {
        float acc = cb4[0];
        #pragma unroll
        for (int tap = 0; tap < 5; tap++) {
            const ushort_t* r = smh + HA + (tid + 3 * tap) * HSTR;
            #pragma unroll
            for (int c8 = 0; c8 < 4; c8++) {
                uint4 q = *(const uint4*)(r + c8 * 8);
                const float* wp = cw4 + (c8 * 8) * 5 + tap;   // uniform -> s_load
                acc = fmaf(wp[0],  __uint_as_float(q.x << 16), acc);
                acc = fmaf(wp[5],  __uint_as_float(q.x & 0xffff0000u), acc);
                acc = fmaf(wp[10], __uint_as_float(q.y << 16), acc);
                acc = fmaf(wp[15], __uint_as_float(q.y & 0xffff0000u), acc);
                acc = fmaf(wp[20], __uint_as_float(q.z << 16), acc);
                acc = fmaf(wp[25], __uint_as_float(q.z & 0xffff0000u), acc);
                acc = fmaf(wp[30], __uint_as_float(q.w << 16), acc);
                acc = fmaf(wp[35], __uint_as_float(q.w & 0xffff0000u), acc);
            }
        }
        smf[SF + tid] = gelu_fast(acc);
    }
    __syncthreads();

    // ---- linear1: 192 -> 50, gelu (exact) ----
    if (tid < 50) {
        float acc = lb1[tid];
        const float* wr = lw1 + tid * 192;
        for (int j = 0; j < 192; j += 4) {
            float4 w = *(const float4*)&wr[j];
            float4 f = *(const float4*)&smf[SF + j];
            acc += w.x*f.x + w.y*f.y + w.z*f.z + w.w*f.w;
        }
        smf[SZ1 + tid] = gelu_exact(acc);
    }
    __syncthreads();

    // ---- linear2: 50 -> 50, gelu (exact) ----
    if (tid < 50) {
        float acc = lb2[tid];
        const float* wr = lw2 + tid * 50;
        for (int j = 0; j < 50; j++) acc = fmaf(wr[j], smf[SZ1 + j], acc);
        smf[SZ2 + tid] = gelu_exact(acc);
    }
    __syncthreads();

    // ---- linear3: 50 -> 15, *100 ----
    if (tid < 15) {
        float acc = lb3[tid];
        const float* wr = lw3 + tid * 50;
        for (int j = 0; j < 50; j++) acc = fmaf(wr[j], smf[SZ2 + j], acc);
        smf[SZV + tid] = acc * 100.0f;
    }
    __syncthreads();

    if (tid >= 9 && tid < 15) out[(size_t)b * 15 + tid] = smf[SZV + tid];

    // ---- 3x3 SVD -> nearest rotation (thread 0) ----
    if (tid == 0) {
        const float A00 = smf[SZV+0], A01 = smf[SZV+1], A02 = smf[SZV+2];
        const float A10 = smf[SZV+3], A11 = smf[SZV+4], A12 = smf[SZV+5];
        const float A20 = smf[SZV+6], A21 = smf[SZV+7], A22 = smf[SZV+8];
        float S00 = A00*A00 + A10*A10 + A20*A20;
        float S01 = A00*A01 + A10*A11 + A20*A21;
        float S02 = A00*A02 + A10*A12 + A20*A22;
        float S11 = A01*A01 + A11*A11 + A21*A21;
        float S12 = A01*A02 + A11*A12 + A21*A22;
        float S22 = A02*A02 + A12*A12 + A22*A22;
        float V00=1.f, V01=0.f, V02=0.f;
        float V10=0.f, V11=1.f, V12=0.f;
        float V20=0.f, V21=0.f, V22=1.f;
        #pragma unroll
        for (int sweep = 0; sweep < 8; sweep++) {
            JROT(S00, S11, S01, S02, S12, V00, V01, V10, V11, V20, V21)
            JROT(S00, S22, S02, S01, S12, V00, V02, V10, V12, V20, V22)
            JROT(S11, S22, S12, S01, S02, V01, V02, V11, V12, V21, V22)
        }
        float e0 = S00, e1 = S11, e2 = S22;
        float va0=V00, va1=V10, va2=V20;
        float vb0=V01, vb1=V11, vb2=V21;
        float vc0=V02, vc1=V12, vc2=V22;
        float sgn = 1.0f, t;
        if (e0 < e1) { t=e0;e0=e1;e1=t; t=va0;va0=vb0;vb0=t; t=va1;va1=vb1;vb1=t; t=va2;va2=vb2;vb2=t; sgn=-sgn; }
        if (e1 < e2) { t=e1;e1=e2;e2=t; t=vb0;vb0=vc0;vc0=t; t=vb1;vb1=vc1;vc1=t; t=vb2;vb2=vc2;vc2=t; sgn=-sgn; }
        if (e0 < e1) { t=e0;e0=e1;e1=t; t=va0;va0=vb0;vb0=t; t=va1;va1=vb1;vb1=t; t=va2;va2=vb2;vb2=t; sgn=-sgn; }
        vc0 *= sgn; vc1 *= sgn; vc2 *= sgn;
        float u10 = A00*va0 + A01*va1 + A02*va2;
        float u11 = A10*va0 + A11*va1 + A12*va2;
        float u12 = A20*va0 + A21*va1 + A22*va2;
        float n1 = sqrtf(u10*u10 + u11*u11 + u12*u12);
        float rn1 = (n1 > 1e-20f) ? 1.0f / n1 : 0.0f;
        u10 *= rn1; u11 *= rn1; u12 *= rn1;
        float u20 = A00*vb0 + A01*vb1 + A02*vb2;
        float u21 = A10*vb0 + A11*vb1 + A12*vb2;
        float u22 = A20*vb0 + A21*vb1 + A22*vb2;
        float d12 = u20*u10 + u21*u11 + u22*u12;
        u20 -= d12*u10; u21 -= d12*u11; u22 -= d12*u12;
        float n2 = sqrtf(u20*u20 + u21*u21 + u22*u22);
        float rn2 = (n2 > 1e-20f) ? 1.0f / n2 : 0.0f;
        u20 *= rn2; u21 *= rn2; u22 *= rn2;
        float u30 = u11*u22 - u12*u21;
        float u31 = u12*u20 - u10*u22;
        float u32 = u10*u21 - u11*u20;
        float* ob = out + (size_t)b * 15;
        ob[0] = u10*va0 + u20*vb0 + u30*vc0;
        ob[1] = u10*va1 + u20*vb1 + u30*vc1;
        ob[2] = u10*va2 + u20*vb2 + u30*vc2;
        ob[3] = u11*va0 + u21*vb0 + u31*vc0;
        ob[4] = u11*va1 + u21*vb1 + u31*vc1;
        ob[5] = u11*va2 + u21*vb2 + u31*vc2;
        ob[6] = u12*va0 + u22*vb0 + u32*vc0;
        ob[7] = u12*va1 + u22*vb1 + u32*vc1;
        ob[8] = u12*va2 + u22*vb2 + u32*vc2;
    }
}

extern "C" void kernel_launch(void* const* d_in, const int* in_sizes, int n_in,
                              void* d_out, int out_size, void* d_ws, size_t ws_size,
                              hipStream_t stream) {
    (void)n_in; (void)out_size; (void)ws_size;
    const float* x     = (const float*)d_in[0];
    const float* calib = (const float*)d_in[1];
    const float* biasv = (const float*)d_in[2];
    const float* cw1   = (const float*)d_in[3];
    const float* cb1   = (const float*)d_in[4];
    const float* cw2   = (const float*)d_in[5];
    const float* cb2   = (const float*)d_in[6];
    const float* cw3   = (const float*)d_in[7];
    const float* cb3   = (const float*)d_in[8];
    const float* cw4   = (const float*)d_in[9];
    const float* cb4   = (const float*)d_in[10];
    const float* lw1   = (const float*)d_in[11];
    const float* lb1   = (const float*)d_in[12];
    const float* lw2   = (const float*)d_in[13];
    const float* lb2   = (const float*)d_in[14];
    const float* lw3   = (const float*)d_in[15];
    const float* lb3   = (const float*)d_in[16];
    float* out = (float*)d_out;
    ushort_t* ws = (ushort_t*)d_ws;
    const int B = in_sizes[0] / 1400;

    hipLaunchKernelGGL(prep_kernel, dim3(22), dim3(512), 0, stream, cw1, cw2, cw3, ws);
    hipLaunchKernelGGL(rminet_kernel, dim3(B), dim3(NTHREADS), 0, stream,
                       x, calib, biasv, cb1, cb2, cb3, cw4, cb4,
                       lw1, lb1, lw2, lb2, lw3, lb3, (const ushort_t*)ws, out);
}